// Round 8
// baseline (468.931 us; speedup 1.0000x reference)
//
#include <hip/hip_runtime.h>
#include <stdint.h>

// VectorQuantization: out[n] = codebook[argmax_k dot(x[n], codebook[k])]
// (argmax invariant to positive per-row scaling -> L2-normalize skipped,
//  and per-row max-norm int8 quantization is equally argmax-preserving)
//
// R11: barrier-free register-direct i8 GEMM. Five LDS schedules (R4-R10)
// all converged at ~100 us because per K-tile the LDS pipe (~1130 cyc: 96KB
// read amplification + 32KB staging writes) and the MFMA pipe (~1306 cyc)
// phase-alternate under blockwide barriers instead of overlapping. The
// quantized inputs are only 12 MB (L2/L3-resident; HBM FETCH measured
// 35 MB), so LDS buys nothing: each wave now independently computes a
// 64x128 output tile over full K, register-double-buffering A(4x16B/lane)
// and B(8x16B/lane) per K=64 chunk straight from L2. No __shared__, no
// s_barrier, no staging, no races possible. Total L2 traffic 16384 waves x
// 96KB = 1.57 GB ~ 44 us at 36 TB/s, overlapped with the 34.8 us MFMA
// floor on a different pipe. A-major wave order (rg fast, cg slow) keeps
// the concurrent per-XCD working set well inside 4 MB L2.
// Registers: acc 128 + A 2x16 + B 2x32 + addr ~= 240 in-loop (top-2 keys
// become live only after the loop) -> launch_bounds(256,1) leaves the
// allocator unconstrained; <=256 gives 2 waves/SIMD naturally.
//
// Pipeline (per wave, no syncs): LOADK(kt+1)->altset; MFMA(kt); compiler
// emits counted vmcnt before first use; WAR is safe because loads into a
// set are textually after the MFMAs that read it (in-order issue).
//
// Epilogue: per-lane top-2 over j (key = D<<3 | (7-j), monotone, free
// lowest-index tie-break), butterfly over 16 col-lanes, ballot winner-lane
// recovery -> top-2 per (row, 128-col-group) = 256 candidates/row; recheck
// loops x4 over them with the same margin + exact-fp64 machinery
// (MARGIN_I = 8000 ~ 29 sigma of int-dot noise; unchanged analysis).
// prep now writes per-block partial maxes (no atomic, no memset launch);
// cb_quant reduces the 1024 partials locally. 4 launches total.

typedef int i32x4 __attribute__((ext_vector_type(4)));

#define M_ROWS 8192
#define DIM 512
#define DIMB 512                      /* bytes per i8 row */
#define K_CODES 16384
#define RG_N 128                      /* 8192/64 row-groups  */
#define CG_N 128                      /* 16384/128 col-groups */
#define MARGIN_I 8000.0f
#define INT_MIN_K (-2147483647 - 1)

__device__ __forceinline__ float absmax4(float4 v) {
  return fmaxf(fmaxf(fabsf(v.x), fabsf(v.y)), fmaxf(fabsf(v.z), fabsf(v.w)));
}

__device__ __forceinline__ unsigned pack4(float a, float b, float c, float d, float inv) {
  const int q0 = __float2int_rn(a * inv), q1 = __float2int_rn(b * inv);
  const int q2 = __float2int_rn(c * inv), q3 = __float2int_rn(d * inv);
  return (unsigned)(q0 & 255) | ((unsigned)(q1 & 255) << 8) |
         ((unsigned)(q2 & 255) << 16) | ((unsigned)(q3 & 255) << 24);
}

// blocks [0,1024): one wave per x row -> per-row absmax quantize to i8.
// blocks [1024,2048): grid-stride absmax over codebook -> pmax[bid-1024]
// (plain store; cb_quant reduces the partials -> no atomic, no memset).
__global__ __launch_bounds__(512) void prep(
    const float* __restrict__ x, const float* __restrict__ cb,
    signed char* __restrict__ xq, float* __restrict__ pmax) {
  __shared__ float sm[8];
  if (blockIdx.x < 1024) {
    const int wv = threadIdx.x >> 6, lane = threadIdx.x & 63;
    const int row = blockIdx.x * 8 + wv;
    const float* xr = x + (size_t)row * DIM + lane * 8;
    const float4 v0 = *(const float4*)xr;
    const float4 v1 = *(const float4*)(xr + 4);
    float m = fmaxf(absmax4(v0), absmax4(v1));
#pragma unroll
    for (int d = 1; d < 64; d <<= 1) m = fmaxf(m, __shfl_xor(m, d));
    const float inv = m > 0.f ? 127.0f / m : 0.f;
    uint2 u;
    u.x = pack4(v0.x, v0.y, v0.z, v0.w, inv);
    u.y = pack4(v1.x, v1.y, v1.z, v1.w, inv);
    ((uint2*)(xq + (size_t)row * DIMB))[lane] = u;
  } else {
    const int n4 = K_CODES * DIM / 4;
    float m = 0.f;
    for (int i = (blockIdx.x - 1024) * 512 + threadIdx.x; i < n4; i += 512 * 1024)
      m = fmaxf(m, absmax4(((const float4*)cb)[i]));
#pragma unroll
    for (int d = 1; d < 64; d <<= 1) m = fmaxf(m, __shfl_xor(m, d));
    if ((threadIdx.x & 63) == 0) sm[threadIdx.x >> 6] = m;
    __syncthreads();
    if (threadIdx.x == 0) {
#pragma unroll
      for (int i = 1; i < 8; ++i) m = fmaxf(m, sm[i]);
      pmax[blockIdx.x - 1024] = m;
    }
  }
}

__global__ __launch_bounds__(256) void cb_quant(
    const float* __restrict__ cb, signed char* __restrict__ cq,
    const float* __restrict__ pmax) {
  __shared__ float sm[4];
  float m = 0.f;
#pragma unroll
  for (int q = 0; q < 4; ++q) m = fmaxf(m, pmax[q * 256 + threadIdx.x]);
#pragma unroll
  for (int d = 1; d < 64; d <<= 1) m = fmaxf(m, __shfl_xor(m, d));
  if ((threadIdx.x & 63) == 0) sm[threadIdx.x >> 6] = m;
  __syncthreads();
  const float mx = fmaxf(fmaxf(sm[0], sm[1]), fmaxf(sm[2], sm[3]));
  const float inv = mx > 0.f ? 127.0f / mx : 0.f;
  const size_t t = (size_t)blockIdx.x * 256 + threadIdx.x;  // 8 elems/thread
  const float* src = cb + t * 8;
  const float4 v0 = *(const float4*)src;
  const float4 v1 = *(const float4*)(src + 4);
  uint2 u;
  u.x = pack4(v0.x, v0.y, v0.z, v0.w, inv);
  u.y = pack4(v1.x, v1.y, v1.z, v1.w, inv);
  ((uint2*)cq)[t] = u;
}

__global__ __launch_bounds__(256, 1) void vq_argmax(
    const signed char* __restrict__ xq, const signed char* __restrict__ cq,
    float* __restrict__ pv, int* __restrict__ pi) {
  const int tid = threadIdx.x;
  const int lane = tid & 63;
  const int wid = blockIdx.x * 4 + (tid >> 6);
  const int rg = wid & (RG_N - 1);      // rg fast -> concurrent waves share cg's B
  const int cg = wid >> 7;
  const int l15 = lane & 15, quad = lane >> 4;
  // fragment lane offset within a [16 rows x 64B] K-chunk panel (row-major,
  // pitch DIMB): lane l reads row l&15, bytes quad*16..+16
  const int vofs = l15 * DIMB + quad * 16;

  const signed char* abase = xq + (size_t)rg * 64 * DIMB + vofs;
  const signed char* bbase = cq + (size_t)cg * 128 * DIMB + vofs;

  i32x4 acc[4][8];
#pragma unroll
  for (int i = 0; i < 4; ++i)
#pragma unroll
    for (int j = 0; j < 8; ++j) acc[i][j] = (i32x4){0, 0, 0, 0};

  i32x4 A0[4], B0[8], A1[4], B1[8];

// 12 global reads (4 A-frags, 8 B-frags) for K-chunk KT into a named set.
#define LOADK(KT, AS, BS)                                                     \
  {                                                                           \
    const signed char* ap_ = abase + (KT) * 64;                               \
    const signed char* bp_ = bbase + (KT) * 64;                               \
    _Pragma("unroll") for (int i = 0; i < 4; ++i)                             \
        AS[i] = *(const i32x4*)(ap_ + i * (16 * DIMB));                       \
    _Pragma("unroll") for (int j = 0; j < 8; ++j)                             \
        BS[j] = *(const i32x4*)(bp_ + j * (16 * DIMB));                       \
  }

#define MFMAS(AS, BS)                                                         \
  {                                                                           \
    _Pragma("unroll") for (int j = 0; j < 8; ++j)                             \
        _Pragma("unroll") for (int i = 0; i < 4; ++i)                         \
            acc[i][j] = __builtin_amdgcn_mfma_i32_16x16x64_i8(                \
                AS[i], BS[j], acc[i][j], 0, 0, 0);                            \
  }

  // depth-1 register pipeline, no barriers anywhere: loads for kt+1 issue
  // before kt's MFMA block (~650 cyc lead >= L2 latency); loads re-filling a
  // set are textually AFTER the MFMAs that read it (WAR-safe, in-order issue)
  LOADK(0, A0, B0);
#pragma unroll 1
  for (int ktp = 0; ktp < 4; ++ktp) {
    const int kt = ktp * 2;
    LOADK(kt + 1, A1, B1);
    MFMAS(A0, B0);
    if (ktp < 3) LOADK(kt + 2, A0, B0);
    MFMAS(A1, B1);
  }
#undef LOADK
#undef MFMAS

  // fold: per (i,r) row-slot, top-2 over the 8 j-columns.
  // key = (D<<3) | (7-j): monotone in D (|D|max ~8.3M, <<3 < 2^31), inverted
  // j code = lowest column wins ties for free.
  int K1[4][4], K2[4][4];
#pragma unroll
  for (int i = 0; i < 4; ++i)
#pragma unroll
    for (int r = 0; r < 4; ++r) { K1[i][r] = INT_MIN_K; K2[i][r] = INT_MIN_K; }
#pragma unroll
  for (int j = 0; j < 8; ++j) {
    const int code = 7 - j;
#pragma unroll
    for (int i = 0; i < 4; ++i)
#pragma unroll
      for (int r = 0; r < 4; ++r) {
        const int k = (acc[i][j][r] << 3) | code;
        const bool gt = k > K1[i][r];
        const int t2 = K2[i][r] > k ? K2[i][r] : k;
        K2[i][r] = gt ? K1[i][r] : t2;
        K1[i][r] = gt ? k : K1[i][r];
      }
  }

  // butterfly-merge top-2 across the 16 column-lanes of each quad; recover
  // winner lane via ballot (lowest l15 = lowest col on duplicate keys)
#pragma unroll
  for (int i = 0; i < 4; ++i)
#pragma unroll
    for (int r = 0; r < 4; ++r) {
      const int p1 = K1[i][r], p2 = K2[i][r];
      int a1 = p1, a2 = p2;
#pragma unroll
      for (int d = 1; d < 16; d <<= 1) {
        const int b1 = __shfl_xor(a1, d);
        const int b2 = __shfl_xor(a2, d);
        const int hi = a1 > b1 ? a1 : b1;
        const int lo = a1 > b1 ? b1 : a1;
        const int mx = a2 > b2 ? a2 : b2;
        a1 = hi;
        a2 = lo > mx ? lo : mx;
      }
      const unsigned long long bl1 = __ballot(p1 == a1);
      const int s1 = __ffsll((unsigned long long)((bl1 >> (quad * 16)) & 0xFFFFull)) - 1;
      const unsigned long long bl2 = __ballot((p2 == a2) || (p1 == a2 && l15 != s1));
      const int s2 = __ffsll((unsigned long long)((bl2 >> (quad * 16)) & 0xFFFFull)) - 1;
      if (l15 == 0) {
        const int j1 = 7 - (a1 & 7), j2 = 7 - (a2 & 7);
        const int col1 = cg * 128 + j1 * 16 + s1;
        const int col2 = cg * 128 + j2 * 16 + s2;
        const int row = rg * 64 + i * 16 + quad * 4 + r;
        const size_t o = (size_t)row * (CG_N * 2) + (size_t)cg * 2;
        pv[o] = (float)(a1 >> 3); pi[o] = col1;       // D in int units; margin
        pv[o + 1] = (float)(a2 >> 3); pi[o + 1] = col2;  // test is relative/row
      }
    }
}

__global__ void recheck_gather(const float* __restrict__ pv, const int* __restrict__ pi,
                               const float* __restrict__ x, const float* __restrict__ cb,
                               float* __restrict__ out) {
  const int row = blockIdx.x;
  const int lane = threadIdx.x;   // 256 candidates = 64 lanes x 4 rounds
  float v[4]; int ci[4];
#pragma unroll
  for (int q = 0; q < 4; ++q) {
    v[q] = pv[(size_t)row * 256 + q * 64 + lane];
    ci[q] = pi[(size_t)row * 256 + q * 64 + lane];
  }
  // local top-1 (lowest index on tie), then wave butterfly
  float m1 = v[0]; int mi1 = ci[0];
#pragma unroll
  for (int q = 1; q < 4; ++q)
    if (v[q] > m1 || (v[q] == m1 && ci[q] < mi1)) { m1 = v[q]; mi1 = ci[q]; }
#pragma unroll
  for (int d = 1; d < 64; d <<= 1) {
    float ov = __shfl_xor(m1, d);
    int oi = __shfl_xor(mi1, d);
    if (ov > m1 || (ov == m1 && oi < mi1)) { m1 = ov; mi1 = oi; }
  }

  bool fl[4]; int tot = 0;
#pragma unroll
  for (int q = 0; q < 4; ++q) {
    fl[q] = (v[q] >= m1 - MARGIN_I);
    tot += __popcll(__ballot(fl[q]));
  }
  int winner;
  if (tot == 1) {
    winner = mi1;   // approx winner ~29 sigma clear of every other candidate
  } else {
    // exact fp64 dot from original fp32 inputs for each flagged candidate
    double e = -1.0e300; int ei = 0x7fffffff;
    const float* xr = x + (size_t)row * DIM;
#pragma unroll
    for (int q = 0; q < 4; ++q) {
      if (fl[q]) {
        const float* cr = cb + (size_t)ci[q] * DIM;
        double s = 0.0;
#pragma unroll 4
        for (int t = 0; t < DIM; t += 4) {
          const float4 a = *(const float4*)(xr + t);
          const float4 b = *(const float4*)(cr + t);
          s += (double)a.x * b.x + (double)a.y * b.y + (double)a.z * b.z + (double)a.w * b.w;
        }
        if (s > e || (s == e && ci[q] < ei)) { e = s; ei = ci[q]; }
      }
    }
#pragma unroll
    for (int d = 1; d < 64; d <<= 1) {
      double oe = __shfl_xor(e, d);
      int oi = __shfl_xor(ei, d);
      if (oe > e || (oe == e && oi < ei)) { e = oe; ei = oi; }
    }
    winner = ei;
  }

  const float4* src = (const float4*)(cb + (size_t)winner * DIM);
  float4* dst = (float4*)(out + (size_t)row * DIM);
  dst[lane] = src[lane];         // 512 f32 = 128 float4, 64 lanes x 2
  dst[lane + 64] = src[lane + 64];
}

extern "C" void kernel_launch(void* const* d_in, const int* in_sizes, int n_in,
                              void* d_out, int out_size, void* d_ws, size_t ws_size,
                              hipStream_t stream) {
  const float* x = (const float*)d_in[0];
  const float* cb = (const float*)d_in[1];
  float* out = (float*)d_out;

  // ws layout: xq(4MB) cq(8MB) pv(8MB) pi(8MB) pmax(4KB)
  signed char* xq = (signed char*)d_ws;
  signed char* cq = xq + (size_t)M_ROWS * DIMB;
  float* pv = (float*)(cq + (size_t)K_CODES * DIMB);
  int* pi = (int*)(pv + (size_t)M_ROWS * CG_N * 2);
  float* pmax = (float*)(pi + (size_t)M_ROWS * CG_N * 2);

  prep<<<2048, 512, 0, stream>>>(x, cb, xq, pmax);
  cb_quant<<<K_CODES * DIM / 8 / 256, 256, 0, stream>>>(cb, cq, pmax);
  vq_argmax<<<(RG_N * CG_N) / 4, 256, 0, stream>>>(xq, cq, pv, pi);
  recheck_gather<<<M_ROWS, 64, 0, stream>>>(pv, pi, x, cb, out);
}

// Round 9
// 355.504 us; speedup vs baseline: 1.3191x; 1.3191x over previous
//
#include <hip/hip_runtime.h>
#include <hip/hip_cooperative_groups.h>
#include <stdint.h>

namespace cg = cooperative_groups;

// VectorQuantization: out[n] = codebook[argmax_k dot(x[n], codebook[k])]
// (argmax invariant to positive per-row scaling -> L2-normalize skipped,
//  and per-row max-norm int8 quantization is equally argmax-preserving)
//
// R12: ONE cooperative kernel. Across R0-R11 the total-minus-vq gap held at
// ~88 us (3 launches) to ~130 us (5 ops) while aux-kernel WORK is only
// ~25 us -- launch/gap overhead ~20 us/op is now the largest line item.
// Fuse all phases into a single hipLaunchCooperativeKernel dispatch with
// grid.sync() between phases:
//   phase 0: x per-row absmax quant (32 rows/block) + cb absmax partials
//   phase 1: reduce 256 partials -> global cb scale -> cb quant (i8)
//   phase 2: vq_argmax == R10's measured body VERBATIM, 2 (rb,split) units
//            per block (256 blocks x 2 = 512 units)
//   phase 3: recheck + gather, 32 rows/block (wave per row x 4 iters)
// Grid 256 blocks x 512 thr = exactly 1 block/CU (vq needs ~240 unified
// regs + 64 KiB LDS -> 8 waves/CU, the resident shape measured in R8/R10)
// -> cooperative co-residency requirement satisfied.
//
// vq phase (unchanged from R10, 100.6 us measured): 2 rotating K-tile LDS
// buffers, stage kt+1 at top of body, 12 ds_read_b128 up front, 32 MFMA in
// two setprio groups with fold halves interleaved, vmcnt(0)+barrier per kt.
// Unit-loop race ledger: unit u+1's prologue stages buf0, whose last
// readers ran at u's kt=30 strictly before the kt30->31 barrier; u's kt31
// reads buf1 only; epilogue is register-only -> no hazard, and the
// prologue's vmcnt(0)+barrier re-syncs.
//
// Carried: per-row absmax x-quant + single global codebook absmax (both
// argmax-invariant); int-dot noise sigma ~276 units, MARGIN_I=8000 (~29
// sigma) + exact-fp64 recheck; zero-bank-conflict XOR chunk swizzle
// (SQ_LDS_BANK_CONFLICT == 0); gll16 staging; packed int top-2 keys
// (D<<5 | inverted 5-bit code -> free lowest-index tie-break); ballot
// winner-lane recovery.

typedef int i32x4 __attribute__((ext_vector_type(4)));

#define M_ROWS 8192
#define DIM 512
#define DIMB 512                      /* bytes per i8 row */
#define K_CODES 16384
#define BM 256
#define BN 256
#define BKB 64                        /* K-tile depth in elements == bytes */
#define NSPLIT 16
#define NT ((K_CODES / NSPLIT) / BN)  /* 4 col-tiles per unit */
#define KT_CT (DIM / BKB)             /* 8 K-tiles per col-tile */
#define G (NT * KT_CT)                /* 32 K-tiles per unit */
#define MARGIN_I 8000.0f
#define INT_MIN_K (-2147483647 - 1)

typedef __attribute__((address_space(1))) uint32_t as1_u32;
typedef __attribute__((address_space(3))) uint32_t as3_u32;

__device__ __forceinline__ void gll16(const void* g, void* l) {
  // async global->LDS, 16B/lane; LDS dest = wave-uniform base + lane*16
  __builtin_amdgcn_global_load_lds((const as1_u32*)(uintptr_t)g,
                                   (as3_u32*)(uintptr_t)l, 16, 0, 0);
}

__device__ __forceinline__ float absmax4(float4 v) {
  return fmaxf(fmaxf(fabsf(v.x), fabsf(v.y)), fmaxf(fabsf(v.z), fabsf(v.w)));
}

__device__ __forceinline__ unsigned pack4(float a, float b, float c, float d, float inv) {
  const int q0 = __float2int_rn(a * inv), q1 = __float2int_rn(b * inv);
  const int q2 = __float2int_rn(c * inv), q3 = __float2int_rn(d * inv);
  return (unsigned)(q0 & 255) | ((unsigned)(q1 & 255) << 8) |
         ((unsigned)(q2 & 255) << 16) | ((unsigned)(q3 & 255) << 24);
}

__global__ __launch_bounds__(512, 2) void vq_all(
    const float* __restrict__ x, const float* __restrict__ cb,
    signed char* __restrict__ xq, signed char* __restrict__ cq,
    float* __restrict__ pmax, float* __restrict__ pv, int* __restrict__ pi,
    float* __restrict__ out) {
  __shared__ signed char lds[2][2][BM * BKB];   // 64 KiB (vq phase)
  __shared__ float smr[8];
  cg::grid_group grid = cg::this_grid();

  const int tid = threadIdx.x;
  const int bid = blockIdx.x;
  const int lane = tid & 63;
  const int wv = tid >> 6;

  // ================= phase 0: x quant + cb absmax partial =================
#pragma unroll
  for (int it = 0; it < 4; ++it) {
    const int row = bid * 32 + wv * 4 + it;
    const float* xr = x + (size_t)row * DIM + lane * 8;
    const float4 v0 = *(const float4*)xr;
    const float4 v1 = *(const float4*)(xr + 4);
    float m = fmaxf(absmax4(v0), absmax4(v1));
#pragma unroll
    for (int d = 1; d < 64; d <<= 1) m = fmaxf(m, __shfl_xor(m, d));
    const float inv = m > 0.f ? 127.0f / m : 0.f;
    uint2 u;
    u.x = pack4(v0.x, v0.y, v0.z, v0.w, inv);
    u.y = pack4(v1.x, v1.y, v1.z, v1.w, inv);
    ((uint2*)(xq + (size_t)row * DIMB))[lane] = u;
  }
  {
    const int n4 = K_CODES * DIM / 4;
    float m = 0.f;
    for (int i = bid * 512 + tid; i < n4; i += 256 * 512)
      m = fmaxf(m, absmax4(((const float4*)cb)[i]));
#pragma unroll
    for (int d = 1; d < 64; d <<= 1) m = fmaxf(m, __shfl_xor(m, d));
    if (lane == 0) smr[wv] = m;
    __syncthreads();
    if (tid == 0) {
#pragma unroll
      for (int i = 1; i < 8; ++i) m = fmaxf(m, smr[i]);
      pmax[bid] = m;
    }
  }
  grid.sync();

  // ================= phase 1: global cb scale + cb quant =================
  {
    float m = pmax[tid & 255];
#pragma unroll
    for (int d = 1; d < 64; d <<= 1) m = fmaxf(m, __shfl_xor(m, d));
    __syncthreads();               // smr free (phase-0 reader done pre-sync)
    if (lane == 0) smr[wv] = m;
    __syncthreads();
    float mx = smr[0];
#pragma unroll
    for (int i = 1; i < 8; ++i) mx = fmaxf(mx, smr[i]);
    const float cinv = mx > 0.f ? 127.0f / mx : 0.f;
    const int n8 = K_CODES * DIM / 8;
    for (int t = bid * 512 + tid; t < n8; t += 256 * 512) {
      const float* src = cb + (size_t)t * 8;
      const float4 v0 = *(const float4*)src;
      const float4 v1 = *(const float4*)(src + 4);
      uint2 u;
      u.x = pack4(v0.x, v0.y, v0.z, v0.w, cinv);
      u.y = pack4(v1.x, v1.y, v1.z, v1.w, cinv);
      ((uint2*)cq)[t] = u;
    }
  }
  grid.sync();

  // ================= phase 2: vq argmax (R10 body, 2 units) ==============
  const int w = wv;
  const int wm = w >> 1, wn = w & 1;       // 4M x 2N wave grid
  const int l15 = lane & 15, quad = lane >> 4;
  const int kq = ((quad ^ ((l15 >> 1) & 3)) << 4);
  const int aoff = (wm * 64 + l15) * BKB + kq;
  const int boff = (wn * 128 + l15) * BKB + kq;

  int eoff0, eoff1, doff0, doff1;
  {
    const int s1 = 512 + tid;
    const int r0 = tid >> 2, r1 = s1 >> 2;
    eoff0 = r0 * DIMB + (((tid & 3) ^ ((r0 >> 1) & 3)) << 4);
    eoff1 = r1 * DIMB + (((s1 & 3) ^ ((r1 >> 1) & 3)) << 4);
    doff0 = (tid & 448) << 4;
    doff1 = (512 + (tid & 448)) << 4;
  }

#pragma unroll 1
  for (int u = 0; u < 2; ++u) {
    const int unit = u * 256 + bid;
    const int rb = unit & 31;
    const int split = unit >> 5;
    const int row0 = rb * BM;
    const signed char* Asrc = xq + (size_t)row0 * DIMB;
    const signed char* Bsrc = cq + (size_t)split * (K_CODES / NSPLIT) * DIMB;

    auto stageA = [&](int t) {
      const signed char* g = Asrc + (t & 7) * BKB;
      signed char* l = &lds[t & 1][0][0];
      gll16(g + eoff0, l + doff0);
      gll16(g + eoff1, l + doff1);
    };
    auto stageB = [&](int t) {
      const signed char* g = Bsrc + (size_t)(t >> 3) * (BN * DIMB) + (t & 7) * BKB;
      signed char* l = &lds[t & 1][1][0];
      gll16(g + eoff0, l + doff0);
      gll16(g + eoff1, l + doff1);
    };

    int K1[4][4], K2[4][4];
#pragma unroll
    for (int i = 0; i < 4; ++i)
#pragma unroll
      for (int r = 0; r < 4; ++r) { K1[i][r] = INT_MIN_K; K2[i][r] = INT_MIN_K; }

    i32x4 acc[4][8];

    auto fold = [&](int j0, int j1, int kt) {
      const int icb = 31 - (kt >> 3) * 8;   // icode_inv = icb - j
#pragma unroll
      for (int j = j0; j < j1; ++j) {
        const int xo = icb - j;
#pragma unroll
        for (int i = 0; i < 4; ++i)
#pragma unroll
          for (int r = 0; r < 4; ++r) {
            const int k = (int)(((unsigned)acc[i][j][r] << 5) | (unsigned)xo);
            const bool gt = k > K1[i][r];
            const int t2 = K2[i][r] > k ? K2[i][r] : k;
            K2[i][r] = gt ? K1[i][r] : t2;
            K1[i][r] = gt ? k : K1[i][r];
          }
      }
    };

    // prologue: stage K-tile 0, drain, sync (also separates unit u-1's
    // buf1 reads from this unit's buf0 staging -- ledger in header)
    stageA(0); stageB(0);
    asm volatile("s_waitcnt vmcnt(0)" ::: "memory");
    __builtin_amdgcn_s_barrier();
    asm volatile("" ::: "memory");

#pragma unroll 1
    for (int kt = 0; kt < G; ++kt) {
      const int bk = kt & 1;
      if (kt + 1 < G) { stageA(kt + 1); stageB(kt + 1); }

      if ((kt & 7) == 0) {
#pragma unroll
        for (int i = 0; i < 4; ++i)
#pragma unroll
          for (int j = 0; j < 8; ++j) acc[i][j] = (i32x4){0, 0, 0, 0};
      }
      const signed char* Ab = &lds[bk][0][0];
      const signed char* Bb = &lds[bk][1][0];

      i32x4 A_[4], B_[8];
#pragma unroll
      for (int i = 0; i < 4; ++i) A_[i] = *(const i32x4*)&Ab[aoff + i * (16 * BKB)];
#pragma unroll
      for (int j = 0; j < 8; ++j) B_[j] = *(const i32x4*)&Bb[boff + j * (16 * BKB)];

      __builtin_amdgcn_s_setprio(1);
#pragma unroll
      for (int j = 0; j < 4; ++j)
#pragma unroll
        for (int i = 0; i < 4; ++i)
          acc[i][j] = __builtin_amdgcn_mfma_i32_16x16x64_i8(A_[i], B_[j], acc[i][j], 0, 0, 0);
      __builtin_amdgcn_s_setprio(0);
      if ((kt & 7) == 7) fold(0, 4, kt);
      __builtin_amdgcn_s_setprio(1);
#pragma unroll
      for (int j = 4; j < 8; ++j)
#pragma unroll
        for (int i = 0; i < 4; ++i)
          acc[i][j] = __builtin_amdgcn_mfma_i32_16x16x64_i8(A_[i], B_[j], acc[i][j], 0, 0, 0);
      __builtin_amdgcn_s_setprio(0);
      if ((kt & 7) == 7) fold(4, 8, kt);

      if (kt + 1 < G) {
        asm volatile("s_waitcnt vmcnt(0)" ::: "memory");
        __builtin_amdgcn_s_barrier();
        asm volatile("" ::: "memory");
      }
    }

    // epilogue: butterfly-merge + ballot winner-lane recovery (reg-only)
    const int nb = split * (K_CODES / NSPLIT);
#pragma unroll
    for (int i = 0; i < 4; ++i)
#pragma unroll
      for (int r = 0; r < 4; ++r) {
        const int p1 = K1[i][r], p2 = K2[i][r];
        int a1 = p1, a2 = p2;
#pragma unroll
        for (int d = 1; d < 16; d <<= 1) {
          const int b1 = __shfl_xor(a1, d);
          const int b2 = __shfl_xor(a2, d);
          const int hi = a1 > b1 ? a1 : b1;
          const int lo = a1 > b1 ? b1 : a1;
          const int mx2 = a2 > b2 ? a2 : b2;
          a1 = hi;
          a2 = lo > mx2 ? lo : mx2;
        }
        const unsigned long long bl1 = __ballot(p1 == a1);
        const int s1 = __ffsll((unsigned long long)((bl1 >> (quad * 16)) & 0xFFFFull)) - 1;
        const unsigned long long bl2 = __ballot((p2 == a2) || (p1 == a2 && l15 != s1));
        const int s2 = __ffsll((unsigned long long)((bl2 >> (quad * 16)) & 0xFFFFull)) - 1;
        if (l15 == 0) {
          const int code1 = 31 - (a1 & 31);
          const int code2 = 31 - (a2 & 31);
          const int col1 = nb + (code1 >> 3) * BN + wn * 128 + (code1 & 7) * 16 + s1;
          const int col2 = nb + (code2 >> 3) * BN + wn * 128 + (code2 & 7) * 16 + s2;
          const int rl = wm * 64 + i * 16 + quad * 4 + r;
          const size_t o = (size_t)(row0 + rl) * 64 + (size_t)(split * 4 + wn * 2);
          pv[o] = (float)(a1 >> 5); pi[o] = col1;
          pv[o + 1] = (float)(a2 >> 5); pi[o + 1] = col2;
        }
      }
  }
  grid.sync();

  // ================= phase 3: recheck + gather (32 rows/block) ============
#pragma unroll 1
  for (int it = 0; it < 4; ++it) {
    const int row = bid * 32 + it * 8 + wv;
    float v = pv[(size_t)row * 64 + lane];
    int ci = pi[(size_t)row * 64 + lane];

    float m1 = v; int mi1 = ci;
#pragma unroll
    for (int d = 1; d < 64; d <<= 1) {
      float ov = __shfl_xor(m1, d);
      int oi = __shfl_xor(mi1, d);
      if (ov > m1 || (ov == m1 && oi < mi1)) { m1 = ov; mi1 = oi; }
    }

    const bool flag = (v >= m1 - MARGIN_I);
    const unsigned long long mask = __ballot(flag);
    int winner;
    if (__popcll(mask) == 1) {
      winner = mi1;   // approx winner ~29 sigma clear of every other candidate
    } else {
      double e = -1.0e300;
      if (flag) {
        const float* xr = x + (size_t)row * DIM;
        const float* cr = cb + (size_t)ci * DIM;
        double s = 0.0;
#pragma unroll 4
        for (int t = 0; t < DIM; t += 4) {
          const float4 a = *(const float4*)(xr + t);
          const float4 b = *(const float4*)(cr + t);
          s += (double)a.x * b.x + (double)a.y * b.y + (double)a.z * b.z + (double)a.w * b.w;
        }
        e = s;
      }
      int ei = flag ? ci : 0x7fffffff;
#pragma unroll
      for (int d = 1; d < 64; d <<= 1) {
        double oe = __shfl_xor(e, d);
        int oi = __shfl_xor(ei, d);
        if (oe > e || (oe == e && oi < ei)) { e = oe; ei = oi; }
      }
      winner = ei;
    }

    const float4* src = (const float4*)(cb + (size_t)winner * DIM);
    float4* dst = (float4*)(out + (size_t)row * DIM);
    dst[lane] = src[lane];
    dst[lane + 64] = src[lane + 64];
  }
}

extern "C" void kernel_launch(void* const* d_in, const int* in_sizes, int n_in,
                              void* d_out, int out_size, void* d_ws, size_t ws_size,
                              hipStream_t stream) {
  const float* x = (const float*)d_in[0];
  const float* cb = (const float*)d_in[1];
  float* out = (float*)d_out;

  // ws layout: xq(4MB) cq(8MB) pv(2MB) pi(2MB) pmax(1KB)
  signed char* xq = (signed char*)d_ws;
  signed char* cq = xq + (size_t)M_ROWS * DIMB;
  float* pv = (float*)(cq + (size_t)K_CODES * DIMB);
  int* pi = (int*)(pv + (size_t)M_ROWS * 64);
  float* pmax = (float*)(pi + (size_t)M_ROWS * 64);

  void* args[] = {(void*)&x, (void*)&cb, (void*)&xq, (void*)&cq,
                  (void*)&pmax, (void*)&pv, (void*)&pi, (void*)&out};
  hipLaunchCooperativeKernel((const void*)vq_all, dim3(256), dim3(512),
                             args, 0, stream);
}

// Round 10
// 217.750 us; speedup vs baseline: 2.1535x; 1.6326x over previous
//
#include <hip/hip_runtime.h>
#include <stdint.h>

// VectorQuantization: out[n] = codebook[argmax_k dot(x[n], codebook[k])]
// (argmax invariant to positive per-row scaling -> L2-normalize skipped,
//  and per-row max-norm int8 quantization is equally argmax-preserving)
//
// R13 = R10 (best measured: vq 101.3 us, total 229.9) + two low-risk cuts:
//  (a) fold VALU rewrite: top-2 update as a branchless max/min network --
//      k=(acc<<5)+code (v_lshl_add), hi=max(k,K1), lo=min(k,K1), K1=hi,
//      K2=max(K2,lo): 4 ops/elem vs 7 (cmp+3 cndmask). Identical keys:
//      invariant K1>=K2 holds; codes make keys unique so tie path is moot.
//      VALUBusy was 41% -- the LARGEST pipe component of vq's serial budget
//      (VALU ~40us > MFMA ~29us > LDS ~30us); fold is its biggest
//      identifiable term.
//  (b) R11's proven prep/cb_quant pair (per-block partial maxes reduced in
//      cb_quant) -> no memset, no atomic: 4 kernel launches total.
// R12 lesson folded in: cooperative fusion REGRESSED (grid.sync ~40us each
// cross-XCD + ~75us cooperative dispatch overhead) -- plain 4-launch
// stream-ordered structure is cheaper. Baseline harness overhead ~70us,
// ~9us/launch incremental.
//
// vq structure (R10, measured): 2 rotating K-tile LDS buffers (64 KiB),
// stage kt+1 at top of body via global_load_lds x4, 12 ds_read_b128 up
// front in need-order, 32 MFMA (i32_16x16x64_i8) in two setprio groups
// with fold halves interleaved, vmcnt(0)+barrier per K-tile.
// Race ledger: during kt, reads hit buf kt&1 only. Stage of kt+1 (top of
// kt) targets buf (kt+1)&1 whose last readers ran during kt-1, strictly
// before the kt-1 -> kt barrier. vmcnt(0) before the end-of-kt barrier
// drains this wave's kt+1 stages; barrier globalizes. Tail: no stage at
// kt=G-1, skip final wait+barrier (epilogue register-only).
//
// Carried: per-row absmax x-quant + single global codebook absmax (both
// argmax-invariant); int-dot noise sigma ~276 int units, MARGIN_I=8000
// (~29 sigma) + exact-fp64 recheck for any candidate within margin;
// zero-bank-conflict XOR chunk swizzle (SQ_LDS_BANK_CONFLICT == 0);
// packed int top-2 keys (D<<5 | inverted 5-bit (coltile,j) code -> free
// lowest-index tie-break); ballot winner-lane recovery.

typedef int i32x4 __attribute__((ext_vector_type(4)));

#define M_ROWS 8192
#define DIM 512
#define DIMB 512                      /* bytes per i8 row */
#define K_CODES 16384
#define BM 256
#define BN 256
#define BKB 64                        /* K-tile depth in elements == bytes */
#define NSPLIT 16
#define NT ((K_CODES / NSPLIT) / BN)  /* 4 col-tiles per block */
#define KT_CT (DIM / BKB)             /* 8 K-tiles per col-tile */
#define G (NT * KT_CT)                /* 32 K-tiles per block */
#define MARGIN_I 8000.0f
#define INT_MIN_K (-2147483647 - 1)

typedef __attribute__((address_space(1))) uint32_t as1_u32;
typedef __attribute__((address_space(3))) uint32_t as3_u32;

__device__ __forceinline__ void gll16(const void* g, void* l) {
  // async global->LDS, 16B/lane; LDS dest = wave-uniform base + lane*16
  __builtin_amdgcn_global_load_lds((const as1_u32*)(uintptr_t)g,
                                   (as3_u32*)(uintptr_t)l, 16, 0, 0);
}

__device__ __forceinline__ float absmax4(float4 v) {
  return fmaxf(fmaxf(fabsf(v.x), fabsf(v.y)), fmaxf(fabsf(v.z), fabsf(v.w)));
}

__device__ __forceinline__ unsigned pack4(float a, float b, float c, float d, float inv) {
  const int q0 = __float2int_rn(a * inv), q1 = __float2int_rn(b * inv);
  const int q2 = __float2int_rn(c * inv), q3 = __float2int_rn(d * inv);
  return (unsigned)(q0 & 255) | ((unsigned)(q1 & 255) << 8) |
         ((unsigned)(q2 & 255) << 16) | ((unsigned)(q3 & 255) << 24);
}

// blocks [0,1024): one wave per x row -> per-row absmax quantize to i8.
// blocks [1024,2048): grid-stride absmax over codebook -> pmax[bid-1024]
// (plain store; cb_quant reduces the partials -> no atomic, no memset).
__global__ __launch_bounds__(512) void prep(
    const float* __restrict__ x, const float* __restrict__ cb,
    signed char* __restrict__ xq, float* __restrict__ pmax) {
  __shared__ float sm[8];
  if (blockIdx.x < 1024) {
    const int wv = threadIdx.x >> 6, lane = threadIdx.x & 63;
    const int row = blockIdx.x * 8 + wv;
    const float* xr = x + (size_t)row * DIM + lane * 8;
    const float4 v0 = *(const float4*)xr;
    const float4 v1 = *(const float4*)(xr + 4);
    float m = fmaxf(absmax4(v0), absmax4(v1));
#pragma unroll
    for (int d = 1; d < 64; d <<= 1) m = fmaxf(m, __shfl_xor(m, d));
    const float inv = m > 0.f ? 127.0f / m : 0.f;
    uint2 u;
    u.x = pack4(v0.x, v0.y, v0.z, v0.w, inv);
    u.y = pack4(v1.x, v1.y, v1.z, v1.w, inv);
    ((uint2*)(xq + (size_t)row * DIMB))[lane] = u;
  } else {
    const int n4 = K_CODES * DIM / 4;
    float m = 0.f;
    for (int i = (blockIdx.x - 1024) * 512 + threadIdx.x; i < n4; i += 512 * 1024)
      m = fmaxf(m, absmax4(((const float4*)cb)[i]));
#pragma unroll
    for (int d = 1; d < 64; d <<= 1) m = fmaxf(m, __shfl_xor(m, d));
    if ((threadIdx.x & 63) == 0) sm[threadIdx.x >> 6] = m;
    __syncthreads();
    if (threadIdx.x == 0) {
#pragma unroll
      for (int i = 1; i < 8; ++i) m = fmaxf(m, sm[i]);
      pmax[blockIdx.x - 1024] = m;
    }
  }
}

__global__ __launch_bounds__(256) void cb_quant(
    const float* __restrict__ cb, signed char* __restrict__ cq,
    const float* __restrict__ pmax) {
  __shared__ float sm[4];
  float m = 0.f;
#pragma unroll
  for (int q = 0; q < 4; ++q) m = fmaxf(m, pmax[q * 256 + threadIdx.x]);
#pragma unroll
  for (int d = 1; d < 64; d <<= 1) m = fmaxf(m, __shfl_xor(m, d));
  if ((threadIdx.x & 63) == 0) sm[threadIdx.x >> 6] = m;
  __syncthreads();
  const float mx = fmaxf(fmaxf(sm[0], sm[1]), fmaxf(sm[2], sm[3]));
  const float inv = mx > 0.f ? 127.0f / mx : 0.f;
  const size_t t = (size_t)blockIdx.x * 256 + threadIdx.x;  // 8 elems/thread
  const float* src = cb + t * 8;
  const float4 v0 = *(const float4*)src;
  const float4 v1 = *(const float4*)(src + 4);
  uint2 u;
  u.x = pack4(v0.x, v0.y, v0.z, v0.w, inv);
  u.y = pack4(v1.x, v1.y, v1.z, v1.w, inv);
  ((uint2*)cq)[t] = u;
}

__global__ __launch_bounds__(512, 2) void vq_argmax(
    const signed char* __restrict__ xq, const signed char* __restrict__ cq,
    float* __restrict__ pv, int* __restrict__ pi) {
  // 2 rotating single-K-tile buffers x {A,B} x (256 rows x 64B) = 64 KiB
  __shared__ signed char lds[2][2][BM * BKB];

  const int tid = threadIdx.x;
  const int lane = tid & 63;
  const int w = tid >> 6;
  const int wm = w >> 1, wn = w & 1;       // 4M x 2N wave grid
  const int l15 = lane & 15, quad = lane >> 4;
  const int row0 = blockIdx.x * BM;
  const int split = blockIdx.y;
  // swizzled 16B-chunk byte offset for this lane's fragment reads
  const int kq = ((quad ^ ((l15 >> 1) & 3)) << 4);
  const int aoff = (wm * 64 + l15) * BKB + kq;
  const int boff = (wn * 128 + l15) * BKB + kq;

  // staging: slot s = r*512+tid holds logical chunk (row=s>>2, kc=(s&3)^((row>>1)&3))
  int eoff0, eoff1, doff0, doff1;
  {
    const int s1 = 512 + tid;
    const int r0 = tid >> 2, r1 = s1 >> 2;
    eoff0 = r0 * DIMB + (((tid & 3) ^ ((r0 >> 1) & 3)) << 4);
    eoff1 = r1 * DIMB + (((s1 & 3) ^ ((r1 >> 1) & 3)) << 4);
    doff0 = (tid & 448) << 4;
    doff1 = (512 + (tid & 448)) << 4;
  }
  const signed char* Asrc = xq + (size_t)row0 * DIMB;
  const signed char* Bsrc = cq + (size_t)split * (K_CODES / NSPLIT) * DIMB;

  auto stageA = [&](int t) {
    const signed char* g = Asrc + (t & 7) * BKB;
    signed char* l = &lds[t & 1][0][0];
    gll16(g + eoff0, l + doff0);
    gll16(g + eoff1, l + doff1);
  };
  auto stageB = [&](int t) {
    const signed char* g = Bsrc + (size_t)(t >> 3) * (BN * DIMB) + (t & 7) * BKB;
    signed char* l = &lds[t & 1][1][0];
    gll16(g + eoff0, l + doff0);
    gll16(g + eoff1, l + doff1);
  };

  // packed top-2 int keys per (i,r) row-slot: key = (D<<5) + icode_inv
  int K1[4][4], K2[4][4];
#pragma unroll
  for (int i = 0; i < 4; ++i)
#pragma unroll
    for (int r = 0; r < 4; ++r) { K1[i][r] = INT_MIN_K; K2[i][r] = INT_MIN_K; }

  i32x4 acc[4][8];

  // branchless 4-op top-2 update: v_lshl_add + max + min + max.
  // Invariant K1 >= K2; identical keys to the old cmp/cndmask form.
  auto fold = [&](int j0, int j1, int kt) {
    const int icb = 31 - (kt >> 3) * 8;   // icode_inv = icb - j
#pragma unroll
    for (int j = j0; j < j1; ++j) {
      const int xo = icb - j;
#pragma unroll
      for (int i = 0; i < 4; ++i)
#pragma unroll
        for (int r = 0; r < 4; ++r) {
          const int k = (int)(((unsigned)acc[i][j][r] << 5)) + xo;
          const int hi = k > K1[i][r] ? k : K1[i][r];
          const int lo = k > K1[i][r] ? K1[i][r] : k;
          K1[i][r] = hi;
          K2[i][r] = K2[i][r] > lo ? K2[i][r] : lo;
        }
    }
  };

  // prologue: stage K-tile 0, drain, sync
  stageA(0); stageB(0);
  asm volatile("s_waitcnt vmcnt(0)" ::: "memory");
  __builtin_amdgcn_s_barrier();
  asm volatile("" ::: "memory");

#pragma unroll 1
  for (int kt = 0; kt < G; ++kt) {
    const int bk = kt & 1;
    // stage kt+1 FIRST (max in-flight time before the end-of-tile drain)
    if (kt + 1 < G) { stageA(kt + 1); stageB(kt + 1); }

    if ((kt & 7) == 0) {
#pragma unroll
      for (int i = 0; i < 4; ++i)
#pragma unroll
        for (int j = 0; j < 8; ++j) acc[i][j] = (i32x4){0, 0, 0, 0};
    }
    const signed char* Ab = &lds[bk][0][0];
    const signed char* Bb = &lds[bk][1][0];

    // all 12 fragment reads up front in need-order; counted lgkm lets the
    // later B reads complete under the first MFMA group
    i32x4 A_[4], B_[8];
#pragma unroll
    for (int i = 0; i < 4; ++i) A_[i] = *(const i32x4*)&Ab[aoff + i * (16 * BKB)];
#pragma unroll
    for (int j = 0; j < 8; ++j) B_[j] = *(const i32x4*)&Bb[boff + j * (16 * BKB)];

    __builtin_amdgcn_s_setprio(1);
#pragma unroll
    for (int j = 0; j < 4; ++j)
#pragma unroll
      for (int i = 0; i < 4; ++i)
        acc[i][j] = __builtin_amdgcn_mfma_i32_16x16x64_i8(A_[i], B_[j], acc[i][j], 0, 0, 0);
    __builtin_amdgcn_s_setprio(0);
    if ((kt & 7) == 7) fold(0, 4, kt);   // VALU half-fold under next MFMA group
    __builtin_amdgcn_s_setprio(1);
#pragma unroll
    for (int j = 4; j < 8; ++j)
#pragma unroll
      for (int i = 0; i < 4; ++i)
        acc[i][j] = __builtin_amdgcn_mfma_i32_16x16x64_i8(A_[i], B_[j], acc[i][j], 0, 0, 0);
    __builtin_amdgcn_s_setprio(0);
    if ((kt & 7) == 7) fold(4, 8, kt);

    // drain this wave's kt+1 stages, then globalize
    if (kt + 1 < G) {
      asm volatile("s_waitcnt vmcnt(0)" ::: "memory");
      __builtin_amdgcn_s_barrier();
      asm volatile("" ::: "memory");
    }
  }

  // butterfly-merge top-2 across the 16 column-lanes of each quad, recover
  // winner lane via ballot (first set bit = lowest l15 = lowest index on tie)
  const int nb = split * (K_CODES / NSPLIT);
#pragma unroll
  for (int i = 0; i < 4; ++i)
#pragma unroll
    for (int r = 0; r < 4; ++r) {
      const int p1 = K1[i][r], p2 = K2[i][r];
      int a1 = p1, a2 = p2;
#pragma unroll
      for (int d = 1; d < 16; d <<= 1) {
        const int b1 = __shfl_xor(a1, d);
        const int b2 = __shfl_xor(a2, d);
        const int hi = a1 > b1 ? a1 : b1;
        const int lo = a1 > b1 ? b1 : a1;
        const int mx = a2 > b2 ? a2 : b2;
        a1 = hi;
        a2 = lo > mx ? lo : mx;
      }
      const unsigned long long bl1 = __ballot(p1 == a1);
      const int s1 = __ffsll((unsigned long long)((bl1 >> (quad * 16)) & 0xFFFFull)) - 1;
      const unsigned long long bl2 = __ballot((p2 == a2) || (p1 == a2 && l15 != s1));
      const int s2 = __ffsll((unsigned long long)((bl2 >> (quad * 16)) & 0xFFFFull)) - 1;
      if (l15 == 0) {
        const int code1 = 31 - (a1 & 31);
        const int code2 = 31 - (a2 & 31);
        const int col1 = nb + (code1 >> 3) * BN + wn * 128 + (code1 & 7) * 16 + s1;
        const int col2 = nb + (code2 >> 3) * BN + wn * 128 + (code2 & 7) * 16 + s2;
        const int rl = wm * 64 + i * 16 + quad * 4 + r;
        const size_t o = (size_t)(row0 + rl) * 64 + (size_t)(split * 4 + wn * 2);
        pv[o] = (float)(a1 >> 5); pi[o] = col1;       // D in int units; margin
        pv[o + 1] = (float)(a2 >> 5); pi[o + 1] = col2;  // test is relative/row
      }
    }
}

__global__ void recheck_gather(const float* __restrict__ pv, const int* __restrict__ pi,
                               const float* __restrict__ x, const float* __restrict__ cb,
                               float* __restrict__ out) {
  const int row = blockIdx.x;
  const int lane = threadIdx.x;   // 64 candidates = 16 splits x 2 halves x top-2
  float v = pv[(size_t)row * 64 + lane];
  int ci = pi[(size_t)row * 64 + lane];

  // wave max with lowest-index tie-break
  float m1 = v; int mi1 = ci;
#pragma unroll
  for (int d = 1; d < 64; d <<= 1) {
    float ov = __shfl_xor(m1, d);
    int oi = __shfl_xor(mi1, d);
    if (ov > m1 || (ov == m1 && oi < mi1)) { m1 = ov; mi1 = oi; }
  }

  const bool flag = (v >= m1 - MARGIN_I);
  const unsigned long long mask = __ballot(flag);
  int winner;
  if (__popcll(mask) == 1) {
    winner = mi1;   // approx winner is ~29-sigma clear of every other candidate
  } else {
    // exact fp64 dot from original fp32 inputs for each flagged candidate
    double e = -1.0e300;
    if (flag) {
      const float* xr = x + (size_t)row * DIM;
      const float* cr = cb + (size_t)ci * DIM;
      double s = 0.0;
#pragma unroll 4
      for (int t = 0; t < DIM; t += 4) {
        const float4 a = *(const float4*)(xr + t);
        const float4 b = *(const float4*)(cr + t);
        s += (double)a.x * b.x + (double)a.y * b.y + (double)a.z * b.z + (double)a.w * b.w;
      }
      e = s;
    }
    int ei = flag ? ci : 0x7fffffff;
#pragma unroll
    for (int d = 1; d < 64; d <<= 1) {
      double oe = __shfl_xor(e, d);
      int oi = __shfl_xor(ei, d);
      if (oe > e || (oe == e && oi < ei)) { e = oe; ei = oi; }
    }
    winner = ei;
  }

  const float4* src = (const float4*)(cb + (size_t)winner * DIM);
  float4* dst = (float4*)(out + (size_t)row * DIM);
  dst[lane] = src[lane];         // 512 f32 = 128 float4, 64 lanes x 2
  dst[lane + 64] = src[lane + 64];
}

extern "C" void kernel_launch(void* const* d_in, const int* in_sizes, int n_in,
                              void* d_out, int out_size, void* d_ws, size_t ws_size,
                              hipStream_t stream) {
  const float* x = (const float*)d_in[0];
  const float* cb = (const float*)d_in[1];
  float* out = (float*)d_out;

  // ws layout: xq(4MB) cq(8MB) pv(2MB) pi(2MB) pmax(4KB)
  signed char* xq = (signed char*)d_ws;
  signed char* cq = xq + (size_t)M_ROWS * DIMB;
  float* pv = (float*)(cq + (size_t)K_CODES * DIMB);
  int* pi = (int*)(pv + (size_t)M_ROWS * 64);
  float* pmax = (float*)(pi + (size_t)M_ROWS * 64);

  prep<<<2048, 512, 0, stream>>>(x, cb, xq, pmax);
  cb_quant<<<K_CODES * DIM / 8 / 256, 256, 0, stream>>>(cb, cq, pmax);
  vq_argmax<<<dim3(M_ROWS / BM, NSPLIT), 512, 0, stream>>>(xq, cq, pv, pi);
  recheck_gather<<<M_ROWS, 64, 0, stream>>>(pv, pi, x, cb, out);
}